// Round 10
// baseline (26.273 us; speedup 1.0000x reference)
//
#include <hip/hip_runtime.h>

// Depthwise causal FIR conv1d.
// x: (B, L, H, D) fp32, filters: (H, D, K) fp32, y: (B, L, H, D) fp32
// y[b,l,c] = sum_k filt[c,k] * x[b, l-6+k, c]   (zero-padded for l-6+k < 0)
// C = H*D = 1024 contiguous innermost -> vectorize channels as 4-wide vectors.
//
// Tuning history (measured):
//   LCHUNK=32, 512 blk:          26.91 us
//   LCHUNK=16, 1024 blk:         29.06 us  (halo/instr overhead; nt-store neutral)
//   LCHUNK=64, 256 blk:          27.53 us  (1 wave/SIMD latency-exposed)
//   + XCD swizzle:               26.84 us  (neutral)
//   + 8-row load pipeline:       25.79 us  (MLP exposure confirmed)
//   + full 38-row burst:         25.21 us  <- champion (filters last)
//   + filters-first:             25.63 us  (slight regression / noise)
// R10: dependency-ordered issue — rows 0..13, then filters, then rows 14..37.
// Head of queue = exactly what output 0 needs; stores overlap ~24 in-flight
// row loads. If neutral vs 25.2: compiler canonicalizes load order and the
// structural roofline (85% of m13 copy ceiling, minimal traffic) stands.

typedef float f32x4 __attribute__((ext_vector_type(4)));

constexpr int B_ = 4;
constexpr int L_ = 4096;
constexpr int H_ = 16;
constexpr int D_ = 64;
constexpr int K_ = 7;
constexpr int C_ = H_ * D_;      // 1024
constexpr int C4_ = C_ / 4;      // 256 channel-groups of 4
constexpr int LCHUNK = 32;       // L rows per block
constexpr int NCHUNK = L_ / LCHUNK;  // 128
constexpr int NBLK = B_ * NCHUNK;    // 512
constexpr int NXCD = 8;
constexpr int PER_XCD = NBLK / NXCD; // 64
constexpr int NROWS = LCHUNK + K_ - 1;  // 38 rows per chunk

__global__ __launch_bounds__(256)
void dwfir_kernel(const float* __restrict__ x,
                  const float* __restrict__ filt,
                  float* __restrict__ y) {
    const int c4 = threadIdx.x;              // 0..255 -> channels 4*c4 .. 4*c4+3
    const int bid = blockIdx.x;
    const int chunk = (bid & (NXCD - 1)) * PER_XCD + (bid >> 3);
    const int b  = chunk / NCHUNK;
    const int l0 = (chunk % NCHUNK) * LCHUNK;

    const f32x4* xv = reinterpret_cast<const f32x4*>(x);
    f32x4*       yv = reinterpret_cast<f32x4*>(y);

    // row i (i=0..37) lives at global L-index l0-6+i
    const f32x4* xrow = xv + (size_t)(b * L_ + l0 - 6) * C4_ + c4;
    f32x4*       yrow = yv + (size_t)(b * L_ + l0) * C4_ + c4;

    f32x4 row[NROWS];   // fully statically indexed -> registers
    const f32x4* fv = reinterpret_cast<const f32x4*>(filt) + c4 * 7;
    f32x4 ft[7];

    // ---- issue order: rows 0..13 (output-0 deps + lookahead), filters,
    //      rows 14..37. Everything before any compute.
    if (l0 >= 6) {       // uniform branch; true for 508/512 blocks
        #pragma unroll
        for (int i = 0; i < 14; ++i)
            row[i] = xrow[(size_t)i * C4_];
        #pragma unroll
        for (int i = 0; i < 7; ++i) ft[i] = fv[i];
        #pragma unroll
        for (int i = 14; i < NROWS; ++i)
            row[i] = xrow[(size_t)i * C4_];
    } else {             // l0 == 0 blocks: zero-pad the left halo
        #pragma unroll
        for (int i = 0; i < 14; ++i) {
            const int l = l0 - 6 + i;
            if (l >= 0) row[i] = xrow[(size_t)i * C4_];
            else        row[i] = (f32x4)(0.f);
        }
        #pragma unroll
        for (int i = 0; i < 7; ++i) ft[i] = fv[i];
        #pragma unroll
        for (int i = 14; i < NROWS; ++i)
            row[i] = xrow[(size_t)i * C4_];
    }

    // unpack filters to scalars (register renames)
    float ff[28];
    #pragma unroll
    for (int i = 0; i < 7; ++i) {
        ff[4 * i + 0] = ft[i].x;
        ff[4 * i + 1] = ft[i].y;
        ff[4 * i + 2] = ft[i].z;
        ff[4 * i + 3] = ft[i].w;
    }
    // ff[ch*7 + k] = filt[4*c4 + ch][k]

    // ---- compute + store all 32 outputs; output j waits only rows 0..j+6
    #pragma unroll
    for (int j = 0; j < LCHUNK; ++j) {
        f32x4 acc;
        acc.x = ff[0]  * row[j].x;
        acc.y = ff[7]  * row[j].y;
        acc.z = ff[14] * row[j].z;
        acc.w = ff[21] * row[j].w;
        #pragma unroll
        for (int k = 1; k < 7; ++k) {
            acc.x = fmaf(ff[k],      row[j + k].x, acc.x);
            acc.y = fmaf(ff[7 + k],  row[j + k].y, acc.y);
            acc.z = fmaf(ff[14 + k], row[j + k].z, acc.z);
            acc.w = fmaf(ff[21 + k], row[j + k].w, acc.w);
        }
        yrow[(size_t)j * C4_] = acc;
    }
}

extern "C" void kernel_launch(void* const* d_in, const int* in_sizes, int n_in,
                              void* d_out, int out_size, void* d_ws, size_t ws_size,
                              hipStream_t stream) {
    const float* x    = (const float*)d_in[0];
    const float* filt = (const float*)d_in[1];
    float*       y    = (float*)d_out;

    dim3 grid(NBLK);    // 512 blocks
    dim3 block(256);
    dwfir_kernel<<<grid, block, 0, stream>>>(x, filt, y);
}

// Round 11
// 25.087 us; speedup vs baseline: 1.0473x; 1.0473x over previous
//
#include <hip/hip_runtime.h>

// Depthwise causal FIR conv1d — FINAL (R8 champion, reverted after R9/R10
// issue-order experiments regressed).
// x: (B, L, H, D) fp32, filters: (H, D, K) fp32, y: (B, L, H, D) fp32
// y[b,l,c] = sum_k filt[c,k] * x[b, l-6+k, c]   (zero-padded for l-6+k < 0)
// C = H*D = 1024 contiguous innermost -> vectorize channels as 4-wide vectors.
//
// Tuning history (measured):
//   LCHUNK=32, 512 blk:          26.91 us
//   LCHUNK=16, 1024 blk:         29.06 us  (halo/instr overhead; nt-store neutral)
//   LCHUNK=64, 256 blk:          27.53 us  (1 wave/SIMD latency-exposed)
//   + XCD swizzle:               26.84 us  (neutral)
//   + 8-row load pipeline:       25.79 us  (MLP exposure confirmed)
//   + full 38-row burst:         25.21 us  <- CHAMPION (this kernel)
//   + filters-first:             25.63 us  (regression)
//   + split dependency order:    26.27 us  (regression)
// 25.21 us = 5.32 TB/s effective = 85% of m13 float4-copy ceiling (6.29 TB/s,
// same 1:1 R:W mix); residual is ~1-1.5 us fixed dispatch cost + mixed-stream
// overhead. Traffic is minimal; all structural axes bracketed. Roofline.

typedef float f32x4 __attribute__((ext_vector_type(4)));

constexpr int B_ = 4;
constexpr int L_ = 4096;
constexpr int H_ = 16;
constexpr int D_ = 64;
constexpr int K_ = 7;
constexpr int C_ = H_ * D_;      // 1024
constexpr int C4_ = C_ / 4;      // 256 channel-groups of 4
constexpr int LCHUNK = 32;       // L rows per block
constexpr int NCHUNK = L_ / LCHUNK;  // 128
constexpr int NBLK = B_ * NCHUNK;    // 512
constexpr int NXCD = 8;
constexpr int PER_XCD = NBLK / NXCD; // 64
constexpr int NROWS = LCHUNK + K_ - 1;  // 38 rows per chunk

__global__ __launch_bounds__(256)
void dwfir_kernel(const float* __restrict__ x,
                  const float* __restrict__ filt,
                  float* __restrict__ y) {
    const int c4 = threadIdx.x;              // 0..255 -> channels 4*c4 .. 4*c4+3
    const int bid = blockIdx.x;
    const int chunk = (bid & (NXCD - 1)) * PER_XCD + (bid >> 3);
    const int b  = chunk / NCHUNK;
    const int l0 = (chunk % NCHUNK) * LCHUNK;

    const f32x4* xv = reinterpret_cast<const f32x4*>(x);
    f32x4*       yv = reinterpret_cast<f32x4*>(y);

    // row i (i=0..37) lives at global L-index l0-6+i
    const f32x4* xrow = xv + (size_t)(b * L_ + l0 - 6) * C4_ + c4;
    f32x4*       yrow = yv + (size_t)(b * L_ + l0) * C4_ + c4;

    f32x4 row[NROWS];   // fully statically indexed -> registers

    // ---- full-depth load burst: all 38 rows issued before any compute
    if (l0 >= 6) {       // uniform branch; true for 508/512 blocks
        #pragma unroll
        for (int i = 0; i < NROWS; ++i)
            row[i] = xrow[(size_t)i * C4_];
    } else {             // l0 == 0 blocks: zero-pad the left halo
        #pragma unroll
        for (int i = 0; i < NROWS; ++i) {
            const int l = l0 - 6 + i;
            if (l >= 0) row[i] = xrow[(size_t)i * C4_];
            else        row[i] = (f32x4)(0.f);
        }
    }

    // ---- filters: 28 consecutive floats per thread (channel-major [c][k])
    const f32x4* fv = reinterpret_cast<const f32x4*>(filt) + c4 * 7;
    float ff[28];
    #pragma unroll
    for (int i = 0; i < 7; ++i) {
        f32x4 t = fv[i];
        ff[4 * i + 0] = t.x;
        ff[4 * i + 1] = t.y;
        ff[4 * i + 2] = t.z;
        ff[4 * i + 3] = t.w;
    }
    // ff[ch*7 + k] = filt[4*c4 + ch][k]

    // ---- compute + store all 32 outputs
    #pragma unroll
    for (int j = 0; j < LCHUNK; ++j) {
        f32x4 acc;
        acc.x = ff[0]  * row[j].x;
        acc.y = ff[7]  * row[j].y;
        acc.z = ff[14] * row[j].z;
        acc.w = ff[21] * row[j].w;
        #pragma unroll
        for (int k = 1; k < 7; ++k) {
            acc.x = fmaf(ff[k],      row[j + k].x, acc.x);
            acc.y = fmaf(ff[7 + k],  row[j + k].y, acc.y);
            acc.z = fmaf(ff[14 + k], row[j + k].z, acc.z);
            acc.w = fmaf(ff[21 + k], row[j + k].w, acc.w);
        }
        yrow[(size_t)j * C4_] = acc;
    }
}

extern "C" void kernel_launch(void* const* d_in, const int* in_sizes, int n_in,
                              void* d_out, int out_size, void* d_ws, size_t ws_size,
                              hipStream_t stream) {
    const float* x    = (const float*)d_in[0];
    const float* filt = (const float*)d_in[1];
    float*       y    = (float*)d_out;

    dim3 grid(NBLK);    // 512 blocks
    dim3 block(256);
    dwfir_kernel<<<grid, block, 0, stream>>>(x, filt, y);
}